// Round 1
// baseline (63.262 us; speedup 1.0000x reference)
//
#include <hip/hip_runtime.h>
#include <math.h>

constexpr int kB = 2, kP = 300, kF = 512, kH = 128, kW = 128, kTH = 512, kTW = 512;
constexpr int kNR = 28;                    // floats per face record
constexpr float kDelta = 7000.0f;
constexpr float kCut = 0.06f;              // band lower-bound cutoff (NDC); p < 1.2e-11 beyond
constexpr float kLogInside = -15.9423847f; // log1p(-(1.0f-1e-7f)) = ln(2^-23)

// Record layout (28 floats):
// 0:x0 1:y0 2:x1 3:y1 4:x2 5:y2
// 6:e0x 7:e0y 8:e1x 9:e1y 10:e2x 11:e2y   (e0=v2-v1, e1=v0-v2, e2=v1-v0)
// 12:z0 13:z1 14:z2 15:inv_area(0 if !front)
// 16:h0 17:h1 18:h2                        (area/len_i : line-distance scales)
// 19:id0 20:id1 21:id2                     (1/(len_i^2+1e-12))
// 22:u0 23:v0 24:u1 25:v1 26:u2 27:v2

__device__ __forceinline__ float seg_d2(float apx, float apy, float abx, float aby,
                                        float inv_den) {
    float t = (apx * abx + apy * aby) * inv_den;
    t = fminf(fmaxf(t, 0.0f), 1.0f);
    float dx = apx - t * abx;
    float dy = apy - t * aby;
    return dx * dx + dy * dy;
}

__device__ __forceinline__ void make_record(const float* __restrict__ pts,
                                            const int* __restrict__ faces,
                                            const float* __restrict__ uvs,
                                            int b, int f, float* r) {
    int i0 = faces[f * 3 + 0], i1 = faces[f * 3 + 1], i2 = faces[f * 3 + 2];
    const float* pb = pts + b * kP * 3;
    float x0 = pb[i0 * 3 + 0], y0 = pb[i0 * 3 + 1], z0 = pb[i0 * 3 + 2];
    float x1 = pb[i1 * 3 + 0], y1 = pb[i1 * 3 + 1], z1 = pb[i1 * 3 + 2];
    float x2 = pb[i2 * 3 + 0], y2 = pb[i2 * 3 + 1], z2 = pb[i2 * 3 + 2];
    float area = (x1 - x0) * (y2 - y0) - (y1 - y0) * (x2 - x0);
    bool front = area > 1e-8f;
    float inv_a = front ? (1.0f / area) : 0.0f;
    float e0x = x2 - x1, e0y = y2 - y1;
    float e1x = x0 - x2, e1y = y0 - y2;
    float e2x = x1 - x0, e2y = y1 - y0;
    float l0 = e0x * e0x + e0y * e0y;
    float l1 = e1x * e1x + e1y * e1y;
    float l2 = e2x * e2x + e2y * e2y;
    const float* ub = uvs + b * kP * 2;
    r[0] = x0; r[1] = y0; r[2] = x1; r[3] = y1; r[4] = x2; r[5] = y2;
    r[6] = e0x; r[7] = e0y; r[8] = e1x; r[9] = e1y; r[10] = e2x; r[11] = e2y;
    r[12] = z0; r[13] = z1; r[14] = z2; r[15] = inv_a;
    r[16] = area * rsqrtf(l0 + 1e-12f);
    r[17] = area * rsqrtf(l1 + 1e-12f);
    r[18] = area * rsqrtf(l2 + 1e-12f);
    r[19] = 1.0f / (l0 + 1e-12f);
    r[20] = 1.0f / (l1 + 1e-12f);
    r[21] = 1.0f / (l2 + 1e-12f);
    r[22] = ub[i0 * 2 + 0]; r[23] = ub[i0 * 2 + 1];
    r[24] = ub[i1 * 2 + 0]; r[25] = ub[i1 * 2 + 1];
    r[26] = ub[i2 * 2 + 0]; r[27] = ub[i2 * 2 + 1];
}

__global__ __launch_bounds__(256) void face_setup(const float* __restrict__ pts,
                                                  const int* __restrict__ faces,
                                                  const float* __restrict__ uvs,
                                                  float* __restrict__ recs) {
    int idx = blockIdx.x * 256 + (int)threadIdx.x;
    if (idx >= kB * kF) return;
    int b = idx / kF, f = idx - b * kF;
    make_record(pts, faces, uvs, b, f, recs + idx * kNR);
}

__device__ __forceinline__ void face_range(const float* rbase, int fbase, int nf,
                                           float px, float py,
                                           float& bestz, int& besti, float& lm) {
    for (int k = 0; k < nf; ++k) {
        int f = fbase + k;
        const float* r = rbase + f * kNR;
        float inv_a = r[15];
        if (inv_a == 0.0f) continue;  // back-facing/degenerate: contributes nothing
        float x0 = r[0], y0 = r[1], x1 = r[2], y1 = r[3], x2 = r[4], y2 = r[5];
        float e0x = r[6], e0y = r[7], e1x = r[8], e1y = r[9], e2x = r[10], e2y = r[11];
        // barycentric (matches reference _edge formulation)
        float w0 = (e0x * (py - y1) - e0y * (px - x1)) * inv_a;
        float w1 = (e1x * (py - y2) - e1y * (px - x2)) * inv_a;
        float w2 = (e2x * (py - y0) - e2y * (px - x0)) * inv_a;
        float minw = fminf(fminf(w0, w1), w2);
        bool inside = minw >= 0.0f;
        float z = w0 * r[12] + w1 * r[13] + w2 * r[14];
        if (inside && z > bestz) { bestz = z; besti = f; }
        if (inside) lm += kLogInside;  // p==1 -> clip -> log1p == ln(2^-23)
        // conservative lower bound on distance to triangle boundary
        float db = fminf(fminf(fabsf(w0) * r[16], fabsf(w1) * r[17]), fabsf(w2) * r[18]);
        bool need = (!inside) && (db < kCut);
        if (need) {
            float dA = seg_d2(px - x0, py - y0, e2x, e2y, r[21]); // seg v0->v1
            float dB = seg_d2(px - x1, py - y1, e0x, e0y, r[19]); // seg v1->v2
            float dC = seg_d2(px - x2, py - y2, e1x, e1y, r[20]); // seg v2->v0
            float d2 = fminf(fminf(dA, dB), dC);
            float p = expf(-kDelta * d2);
            p = fminf(p, 1.0f - 1e-7f);
            lm += log1pf(-p);
        }
    }
}

template <bool WS>
__global__ __launch_bounds__(256) void render_main(const float* __restrict__ pts,
                                                   const int* __restrict__ faces,
                                                   const float* __restrict__ uvs,
                                                   const float* __restrict__ tex,
                                                   const float* __restrict__ grecs,
                                                   float* __restrict__ out) {
    __shared__ float s_bz[256];
    __shared__ int s_bi[256];
    __shared__ float s_lm[256];
    __shared__ float srecs[WS ? kNR : kF * kNR];

    int tile = blockIdx.x;
    int b = tile >> 8;
    int rem = tile & 255;
    int ty = rem >> 4, tx = rem & 15;
    int tid = (int)threadIdx.x;
    int lane = tid & 63;
    int wv = tid >> 6;

    if constexpr (!WS) {
        for (int f = tid; f < kF; f += 256)
            make_record(pts, faces, uvs, b, f, &srecs[f * kNR]);
        __syncthreads();
    }
    const float* rbase;
    if constexpr (WS) rbase = grecs + (size_t)b * kF * kNR;
    else rbase = srecs;

    int pyi = ty * 8 + (lane >> 3);
    int pxi = tx * 8 + (lane & 7);
    float px = ((float)pxi + 0.5f) / 128.0f * 2.0f - 1.0f;
    float py = 1.0f - ((float)pyi + 0.5f) / 128.0f * 2.0f;

    // each wave handles a contiguous quarter of the faces (uniform -> s_load)
    int fbase = __builtin_amdgcn_readfirstlane(wv) * (kF / 4);

    float bestz = -1e9f;
    int besti = -1;
    float lm = 0.0f;
    face_range(rbase, fbase, kF / 4, px, py, bestz, besti, lm);

    s_bz[tid] = bestz;
    s_bi[tid] = besti;
    s_lm[tid] = lm;
    __syncthreads();

    if (tid < 64) {
        float bz = s_bz[tid];
        int bi = s_bi[tid];
        float L = s_lm[tid];
        for (int w = 1; w < 4; ++w) {  // ascending face ranges: strict > == first-max
            float z2 = s_bz[w * 64 + tid];
            int i2 = s_bi[w * 64 + tid];
            L += s_lm[w * 64 + tid];
            if (z2 > bz) { bz = z2; bi = i2; }
        }
        float improb = 1.0f - expf(L);
        float u = 0.0f, v = 0.0f, mask = 0.0f;
        if (bi >= 0) {
            const float* r = rbase + bi * kNR;
            float inv_a = r[15];
            float w0 = (r[6] * (py - r[3]) - r[7] * (px - r[2])) * inv_a;
            float w1 = (r[8] * (py - r[5]) - r[9] * (px - r[4])) * inv_a;
            float w2 = (r[10] * (py - r[1]) - r[11] * (px - r[0])) * inv_a;
            u = w0 * r[22] + w1 * r[24] + w2 * r[26];
            v = w0 * r[23] + w1 * r[25] + w2 * r[27];
            mask = w0 + w1 + w2;
        }
        float uc = fminf(fmaxf(u, 0.0f), 1.0f);
        float vc = fminf(fmaxf(v, 0.0f), 1.0f);
        float fx = uc * (float)(kTW - 1);
        float fy = (1.0f - vc) * (float)(kTH - 1);
        int xi0 = (int)floorf(fx), yi0 = (int)floorf(fy);
        int xi1 = min(xi0 + 1, kTW - 1), yi1 = min(yi0 + 1, kTH - 1);
        float wx = fx - (float)xi0, wy = fy - (float)yi0;
        float w00 = (1.0f - wx) * (1.0f - wy);
        float w01 = wx * (1.0f - wy);
        float w10 = (1.0f - wx) * wy;
        float w11 = wx * wy;
        int o00 = yi0 * kTW + xi0, o01 = yi0 * kTW + xi1;
        int o10 = yi1 * kTW + xi0, o11 = yi1 * kTW + xi1;
        const float* tb = tex + (size_t)b * 3 * kTH * kTW;
        float cols[3];
#pragma unroll
        for (int c = 0; c < 3; ++c) {
            const float* tc = tb + c * kTH * kTW;
            cols[c] = (tc[o00] * w00 + tc[o01] * w01 + tc[o10] * w10 + tc[o11] * w11) * mask;
        }
        int pix = (b * kH + pyi) * kW + pxi;
        out[pix * 3 + 0] = cols[0];
        out[pix * 3 + 1] = cols[1];
        out[pix * 3 + 2] = cols[2];
        out[kB * kH * kW * 3 + pix] = improb;
    }
}

extern "C" void kernel_launch(void* const* d_in, const int* in_sizes, int n_in,
                              void* d_out, int out_size, void* d_ws, size_t ws_size,
                              hipStream_t stream) {
    const float* pts = (const float*)d_in[0];
    const int* faces = (const int*)d_in[1];
    const float* uvs = (const float*)d_in[2];
    const float* tex = (const float*)d_in[3];
    float* out = (float*)d_out;

    const size_t rec_bytes = (size_t)kB * kF * kNR * sizeof(float);
    if (ws_size >= rec_bytes) {
        float* recs = (float*)d_ws;
        face_setup<<<(kB * kF + 255) / 256, 256, 0, stream>>>(pts, faces, uvs, recs);
        render_main<true><<<kB * 16 * 16, 256, 0, stream>>>(pts, faces, uvs, tex, recs, out);
    } else {
        render_main<false><<<kB * 16 * 16, 256, 0, stream>>>(pts, faces, uvs, tex, nullptr, out);
    }
}

// Round 2
// 30.742 us; speedup vs baseline: 2.0578x; 2.0578x over previous
//
#include <hip/hip_runtime.h>
#include <math.h>

constexpr int kB = 2, kP = 300, kF = 512, kH = 128, kW = 128, kTH = 512, kTW = 512;
constexpr float kDelta = 7000.0f;
constexpr float kCut = 0.06f;              // band cutoff: p < 1.2e-11 beyond -> skip
constexpr float kLogInside = -15.9423847f; // log1p(-(1-1e-7f)) = ln(2^-23)

constexpr int kHotF = 16;  // a0,b0,c0,a1,b1,c1,a2,b2,c2,az,bz,cz,h0,h1,h2,orig_face_idx
constexpr int kUvF  = 9;   // ua,ub,uc,va,vb,vc,ma,mb,mc   (u/v/mask affine coeffs)
constexpr size_t kHotOff = 64;  // [0..7]: int counts[2]
constexpr size_t kUvOff  = kHotOff + (size_t)kB * kF * kHotF * sizeof(float);
// total ws need = 64 + 65536 + 36864 = 102,464 B  (round-0 proved ws_size >= 114,688)

__device__ __forceinline__ float seg_d2(float apx, float apy, float abx, float aby,
                                        float inv_den) {
    float t = (apx * abx + apy * aby) * inv_den;
    t = fminf(fmaxf(t, 0.0f), 1.0f);
    float dx = apx - t * abx;
    float dy = apy - t * aby;
    return dx * dx + dy * dy;
}

// One block, 1024 threads: build compacted (order-preserving) front-face records.
__global__ __launch_bounds__(1024) void face_setup(const float* __restrict__ pts,
                                                   const int* __restrict__ faces,
                                                   const float* __restrict__ uvs,
                                                   char* __restrict__ ws) {
    int tid = (int)threadIdx.x;
    int b = tid >> 9, f = tid & 511;
    int i0 = faces[f * 3 + 0], i1 = faces[f * 3 + 1], i2 = faces[f * 3 + 2];
    const float* pb = pts + b * kP * 3;
    float x0 = pb[i0 * 3], y0 = pb[i0 * 3 + 1], z0 = pb[i0 * 3 + 2];
    float x1 = pb[i1 * 3], y1 = pb[i1 * 3 + 1], z1 = pb[i1 * 3 + 2];
    float x2 = pb[i2 * 3], y2 = pb[i2 * 3 + 1], z2 = pb[i2 * 3 + 2];
    float area = (x1 - x0) * (y2 - y0) - (y1 - y0) * (x2 - x0);
    bool front = area > 1e-8f;

    // order-preserving compaction per batch (batch = 8 waves of this block)
    unsigned long long m = __ballot(front);
    int lane = tid & 63, wv = tid >> 6;
    __shared__ int wsum[16];
    int prefix = __popcll(m & ((1ull << lane) - 1ull));
    if (lane == 0) wsum[wv] = __popcll(m);
    __syncthreads();
    int wstart = (b == 0) ? 0 : 8;
    int base = 0;
    for (int w = wstart; w < wv; ++w) base += wsum[w];
    int slot = base + prefix;
    if ((tid & 511) == 0) {
        int t = 0;
        for (int w = 0; w < 8; ++w) t += wsum[wstart + w];
        ((int*)ws)[b] = t;
    }
    if (!front) return;

    float inv_a = 1.0f / area;
    float e0x = x2 - x1, e0y = y2 - y1;
    float e1x = x0 - x2, e1y = y0 - y2;
    float e2x = x1 - x0, e2y = y1 - y0;
    // w_i(px,py) = a_i*px + b_i*py + c_i  (matches reference _edge * inv_area)
    float a0 = -e0y * inv_a, b0 = e0x * inv_a, c0 = (e0y * x1 - e0x * y1) * inv_a;
    float a1 = -e1y * inv_a, b1 = e1x * inv_a, c1 = (e1y * x2 - e1x * y2) * inv_a;
    float a2 = -e2y * inv_a, b2 = e2x * inv_a, c2 = (e2y * x0 - e2x * y0) * inv_a;
    float l0 = e0x * e0x + e0y * e0y;
    float l1 = e1x * e1x + e1y * e1y;
    float l2 = e2x * e2x + e2y * e2y;

    float* hr = (float*)(ws + kHotOff) + ((size_t)b * kF + slot) * kHotF;
    hr[0] = a0;  hr[1] = b0;  hr[2] = c0;
    hr[3] = a1;  hr[4] = b1;  hr[5] = c1;
    hr[6] = a2;  hr[7] = b2;  hr[8] = c2;
    hr[9]  = a0 * z0 + a1 * z1 + a2 * z2;
    hr[10] = b0 * z0 + b1 * z1 + b2 * z2;
    hr[11] = c0 * z0 + c1 * z1 + c2 * z2;
    hr[12] = area * rsqrtf(l0 + 1e-12f);  // |w0|*h0 = dist to line v1-v2
    hr[13] = area * rsqrtf(l1 + 1e-12f);
    hr[14] = area * rsqrtf(l2 + 1e-12f);
    hr[15] = __int_as_float(f);           // original face index (slow path reload)

    const float* ub = uvs + b * kP * 2;
    float u0 = ub[i0 * 2], v0 = ub[i0 * 2 + 1];
    float u1 = ub[i1 * 2], v1 = ub[i1 * 2 + 1];
    float u2 = ub[i2 * 2], v2 = ub[i2 * 2 + 1];
    float* qr = (float*)(ws + kUvOff) + ((size_t)b * kF + slot) * kUvF;
    qr[0] = a0 * u0 + a1 * u1 + a2 * u2;
    qr[1] = b0 * u0 + b1 * u1 + b2 * u2;
    qr[2] = c0 * u0 + c1 * u1 + c2 * u2;
    qr[3] = a0 * v0 + a1 * v1 + a2 * v2;
    qr[4] = b0 * v0 + b1 * v1 + b2 * v2;
    qr[5] = c0 * v0 + c1 * v1 + c2 * v2;
    qr[6] = a0 + a1 + a2;
    qr[7] = b0 + b1 + b2;
    qr[8] = c0 + c1 + c2;
}

// 512 blocks (2 batches x 256 8x8 tiles), 8 waves each: wave w does 1/8 of faces.
__global__ __launch_bounds__(512) void render_main(const float* __restrict__ pts,
                                                   const int* __restrict__ faces,
                                                   const float* __restrict__ tex,
                                                   const char* __restrict__ ws,
                                                   float* __restrict__ out) {
    __shared__ float s_bz[512];
    __shared__ int s_bi[512];
    __shared__ float s_lm[512];

    int tile = (int)blockIdx.x;
    int b = tile >> 8;
    int rem = tile & 255;
    int ty = rem >> 4, tx = rem & 15;
    int tid = (int)threadIdx.x;
    int lane = tid & 63;
    int wv = __builtin_amdgcn_readfirstlane(tid >> 6);

    int pyi = ty * 8 + (lane >> 3);
    int pxi = tx * 8 + (lane & 7);
    float px = ((float)pxi + 0.5f) * (2.0f / 128.0f) - 1.0f;
    float py = 1.0f - ((float)pyi + 0.5f) * (2.0f / 128.0f);

    int n = ((const int*)ws)[b];
    const float* hot = (const float*)(ws + kHotOff) + (size_t)b * kF * kHotF;
    int chunk = (n + 7) >> 3;
    int f0 = wv * chunk;
    int f1 = min(n, f0 + chunk);

    float bestz = -1e9f;
    int besti = -1;
    int icnt = 0;
    float lm = 0.0f;

    for (int f = f0; f < f1; ++f) {
        const float* r = hot + f * kHotF;      // wave-uniform -> s_load_dwordx16
        float4 h0 = *(const float4*)r;
        float4 h1 = *(const float4*)(r + 4);
        float4 h2 = *(const float4*)(r + 8);
        float4 h3 = *(const float4*)(r + 12);
        float w0 = fmaf(h0.x, px, fmaf(h0.y, py, h0.z));
        float w1 = fmaf(h0.w, px, fmaf(h1.x, py, h1.y));
        float w2 = fmaf(h1.z, px, fmaf(h1.w, py, h2.x));
        float minw = fminf(fminf(w0, w1), w2);
        bool inside = minw >= 0.0f;
        float z = fmaf(h2.y, px, fmaf(h2.z, py, h2.w));
        if (inside && z > bestz) { bestz = z; besti = f; }
        icnt += inside ? 1 : 0;
        // conservative lower bound on distance to triangle boundary
        float db = fminf(fminf(fabsf(w0) * h3.x, fabsf(w1) * h3.y), fabsf(w2) * h3.z);
        bool need = (!inside) && (db < kCut);
        if (__any(need)) {
            int of = __float_as_int(h3.w);
            int i0 = faces[of * 3], i1 = faces[of * 3 + 1], i2 = faces[of * 3 + 2];
            const float* pb = pts + b * kP * 3;
            float x0 = pb[i0 * 3], y0 = pb[i0 * 3 + 1];
            float x1 = pb[i1 * 3], y1 = pb[i1 * 3 + 1];
            float x2 = pb[i2 * 3], y2 = pb[i2 * 3 + 1];
            float e2x = x1 - x0, e2y = y1 - y0;
            float e0x = x2 - x1, e0y = y2 - y1;
            float e1x = x0 - x2, e1y = y0 - y2;
            float dA = seg_d2(px - x0, py - y0, e2x, e2y, 1.0f / (e2x * e2x + e2y * e2y + 1e-12f));
            float dB = seg_d2(px - x1, py - y1, e0x, e0y, 1.0f / (e0x * e0x + e0y * e0y + 1e-12f));
            float dC = seg_d2(px - x2, py - y2, e1x, e1y, 1.0f / (e1x * e1x + e1y * e1y + 1e-12f));
            float d2 = fminf(fminf(dA, dB), dC);
            float p = __expf(-kDelta * d2);
            p = fminf(p, 1.0f - 1e-7f);
            float lp = __logf(1.0f - p);   // == log1p(-p): 1-p exact for p>=0.5
            lm += need ? lp : 0.0f;
        }
    }
    lm += (float)icnt * kLogInside;

    s_bz[tid] = bestz;
    s_bi[tid] = besti;
    s_lm[tid] = lm;
    __syncthreads();

    if (tid < 64) {
        float bz = s_bz[tid];
        int bi = s_bi[tid];
        float L = s_lm[tid];
        for (int w = 1; w < 8; ++w) {  // ascending face ranges: strict > == first-max
            float z2 = s_bz[w * 64 + tid];
            int ii = s_bi[w * 64 + tid];
            L += s_lm[w * 64 + tid];
            if (z2 > bz) { bz = z2; bi = ii; }
        }
        float improb = 1.0f - expf(L);
        float u = 0.0f, v = 0.0f, mk = 0.0f;
        if (bi >= 0) {
            const float* q = (const float*)(ws + kUvOff) + ((size_t)b * kF + bi) * kUvF;
            u  = fmaf(q[0], px, fmaf(q[1], py, q[2]));
            v  = fmaf(q[3], px, fmaf(q[4], py, q[5]));
            mk = fmaf(q[6], px, fmaf(q[7], py, q[8]));
        }
        float uc = fminf(fmaxf(u, 0.0f), 1.0f);
        float vc = fminf(fmaxf(v, 0.0f), 1.0f);
        float fx = uc * (float)(kTW - 1);
        float fy = (1.0f - vc) * (float)(kTH - 1);
        int xi0 = (int)floorf(fx), yi0 = (int)floorf(fy);
        int xi1 = min(xi0 + 1, kTW - 1), yi1 = min(yi0 + 1, kTH - 1);
        float wx = fx - (float)xi0, wy = fy - (float)yi0;
        float w00 = (1.0f - wx) * (1.0f - wy);
        float w01 = wx * (1.0f - wy);
        float w10 = (1.0f - wx) * wy;
        float w11 = wx * wy;
        int o00 = yi0 * kTW + xi0, o01 = yi0 * kTW + xi1;
        int o10 = yi1 * kTW + xi0, o11 = yi1 * kTW + xi1;
        const float* tb = tex + (size_t)b * 3 * kTH * kTW;
        float cols[3];
#pragma unroll
        for (int c = 0; c < 3; ++c) {
            const float* tc = tb + c * kTH * kTW;
            cols[c] = (tc[o00] * w00 + tc[o01] * w01 + tc[o10] * w10 + tc[o11] * w11) * mk;
        }
        int pix = (b * kH + pyi) * kW + pxi;
        out[pix * 3 + 0] = cols[0];
        out[pix * 3 + 1] = cols[1];
        out[pix * 3 + 2] = cols[2];
        out[kB * kH * kW * 3 + pix] = improb;
    }
}

extern "C" void kernel_launch(void* const* d_in, const int* in_sizes, int n_in,
                              void* d_out, int out_size, void* d_ws, size_t ws_size,
                              hipStream_t stream) {
    const float* pts = (const float*)d_in[0];
    const int* faces = (const int*)d_in[1];
    const float* uvs = (const float*)d_in[2];
    const float* tex = (const float*)d_in[3];
    float* out = (float*)d_out;
    // ws need: 102,464 B; round-0 established ws_size >= 114,688 B.
    face_setup<<<1, 1024, 0, stream>>>(pts, faces, uvs, (char*)d_ws);
    render_main<<<kB * 256, 512, 0, stream>>>(pts, faces, tex, (const char*)d_ws, out);
}

// Round 3
// 18.533 us; speedup vs baseline: 3.4134x; 1.6588x over previous
//
#include <hip/hip_runtime.h>
#include <math.h>

constexpr int kB = 2, kP = 300, kF = 512, kH = 128, kW = 128, kTH = 512, kTW = 512;
constexpr float kDelta = 7000.0f;
constexpr float kCut = 0.06f;              // band cutoff: p < 1.2e-11 beyond -> skip
constexpr float kLogInside = -15.9423847f; // log1p(-(1-1e-7f)) = ln(2^-23)

__device__ __forceinline__ float seg_d2(float apx, float apy, float abx, float aby) {
    float len2 = fmaf(abx, abx, aby * aby) + 1e-12f;
    float t = fmaf(apx, abx, apy * aby) * __builtin_amdgcn_rcpf(len2);
    t = fminf(fmaxf(t, 0.0f), 1.0f);
    float dx = fmaf(-t, abx, apx);
    float dy = fmaf(-t, aby, apy);
    return fmaf(dx, dx, dy * dy);
}

// One fused kernel. Grid: 512 blocks = 2 batches x 256 tiles (8x8 px).
// Block: 512 threads = 8 waves; all waves share the tile's 64 pixels,
// faces are interleaved across waves (face = lane*8 + wave).
__global__ __launch_bounds__(512) void render_all(const float* __restrict__ pts,
                                                  const int* __restrict__ faces,
                                                  const float* __restrict__ uvs,
                                                  const float* __restrict__ tex,
                                                  float* __restrict__ out) {
    // hot[slot]: h0=(a0,b0,c0,a1) h1=(b1,c1,a2,b2) h2=(c2,az,bz,cz) h3=(d0,d1,d2,origf)
    __shared__ float4 s_hot4[kF * 4];   // 32 KB
    __shared__ float4 s_vtx4[kF * 2];   // 16 KB: (x0,y0,x1,y1),(x2,y2,-,-)
    __shared__ unsigned s_bb[kF];       // 2 KB packed tile ranges
    __shared__ int s_wsum[8];
    __shared__ float s_bz[512];
    __shared__ int s_bi[512];
    __shared__ float s_lm[512];

    int tile = (int)blockIdx.x;
    int b = tile >> 8;
    int rem = tile & 255;
    int ty = rem >> 4, tx = rem & 15;
    int tid = (int)threadIdx.x;
    int lane = tid & 63;
    int wv = tid >> 6;

    // ---------- setup phase: thread tid processes face tid for batch b ----------
    {
        int f = tid;
        int i0 = faces[f * 3 + 0], i1 = faces[f * 3 + 1], i2 = faces[f * 3 + 2];
        const float* pb = pts + b * kP * 3;
        float x0 = pb[i0 * 3], y0 = pb[i0 * 3 + 1], z0 = pb[i0 * 3 + 2];
        float x1 = pb[i1 * 3], y1 = pb[i1 * 3 + 1], z1 = pb[i1 * 3 + 2];
        float x2 = pb[i2 * 3], y2 = pb[i2 * 3 + 1], z2 = pb[i2 * 3 + 2];
        float area = (x1 - x0) * (y2 - y0) - (y1 - y0) * (x2 - x0);
        bool front = area > 1e-8f;

        s_bb[f] = 1u;  // pre-fill EMPTY (txl=1 > txh=0) for slots never written
        unsigned long long bal = __ballot(front);
        if (lane == 0) s_wsum[wv] = __popcll(bal);
        __syncthreads();  // wsum ready AND pre-fill done

        int base = 0;
#pragma unroll
        for (int w = 0; w < 8; ++w) base += (w < wv) ? s_wsum[w] : 0;
        int slot = base + __popcll(bal & ((1ull << lane) - 1ull));

        if (front) {
            float inv_a = 1.0f / area;
            float e0x = x2 - x1, e0y = y2 - y1;
            float e1x = x0 - x2, e1y = y0 - y2;
            float e2x = x1 - x0, e2y = y1 - y0;
            // w_i(px,py) = a_i*px + b_i*py + c_i (== reference _edge * inv_area)
            float a0 = -e0y * inv_a, b0 = e0x * inv_a, c0 = (e0y * x1 - e0x * y1) * inv_a;
            float a1 = -e1y * inv_a, b1 = e1x * inv_a, c1 = (e1y * x2 - e1x * y2) * inv_a;
            float a2 = -e2y * inv_a, b2 = e2x * inv_a, c2 = (e2y * x0 - e2x * y0) * inv_a;
            float l0 = fmaf(e0x, e0x, e0y * e0y);
            float l1 = fmaf(e1x, e1x, e1y * e1y);
            float l2 = fmaf(e2x, e2x, e2y * e2y);
            s_hot4[slot * 4 + 0] = make_float4(a0, b0, c0, a1);
            s_hot4[slot * 4 + 1] = make_float4(b1, c1, a2, b2);
            s_hot4[slot * 4 + 2] = make_float4(c2,
                                               a0 * z0 + a1 * z1 + a2 * z2,
                                               b0 * z0 + b1 * z1 + b2 * z2,
                                               c0 * z0 + c1 * z1 + c2 * z2);
            s_hot4[slot * 4 + 3] = make_float4(area * rsqrtf(l0 + 1e-12f),
                                               area * rsqrtf(l1 + 1e-12f),
                                               area * rsqrtf(l2 + 1e-12f),
                                               __int_as_float(f));
            s_vtx4[slot * 2 + 0] = make_float4(x0, y0, x1, y1);
            s_vtx4[slot * 2 + 1] = make_float4(x2, y2, 0.0f, 0.0f);
            // kCut-inflated bbox -> inclusive tile index range, packed 4x4 bits
            float bx0 = fminf(fminf(x0, x1), x2) - kCut;
            float bx1 = fmaxf(fmaxf(x0, x1), x2) + kCut;
            float by0 = fminf(fminf(y0, y1), y2) - kCut;
            float by1 = fmaxf(fmaxf(y0, y1), y2) + kCut;
            int txl = (int)ceilf((64.0f * (bx0 + 1.0f) - 7.5f) * 0.125f - 1e-4f);
            int txh = (int)floorf((64.0f * (bx1 + 1.0f) - 0.5f) * 0.125f + 1e-4f);
            int tyl = (int)ceilf((64.0f * (1.0f - by1) - 7.5f) * 0.125f - 1e-4f);
            int tyh = (int)floorf((64.0f * (1.0f - by0) - 0.5f) * 0.125f + 1e-4f);
            txl = max(txl, 0); tyl = max(tyl, 0);
            txh = min(txh, 15); tyh = min(tyh, 15);
            unsigned pk = (txl > txh || tyl > tyh)
                              ? 1u
                              : ((unsigned)txl | ((unsigned)txh << 4) |
                                 ((unsigned)tyl << 8) | ((unsigned)tyh << 12));
            s_bb[slot] = pk;
        }
    }
    __syncthreads();

    // ---------- render phase ----------
    int pyi = ty * 8 + (lane >> 3);
    int pxi = tx * 8 + (lane & 7);
    float px = ((float)pxi + 0.5f) * (2.0f / 128.0f) - 1.0f;
    float py = 1.0f - ((float)pyi + 0.5f) * (2.0f / 128.0f);

    // wave wv owns faces {lane*8+wv}: ballot-cull its 64 candidates vs this tile
    unsigned bbv = s_bb[(lane << 3) + wv];
    bool ov = ((int)(bbv & 15u) <= tx) & (tx <= (int)((bbv >> 4) & 15u)) &
              ((int)((bbv >> 8) & 15u) <= ty) & (ty <= (int)((bbv >> 12) & 15u));
    unsigned long long m = __ballot(ov);

    float bestz = -1e9f;
    int besti = -1, icnt = 0;
    float lm = 0.0f;

    while (m) {
        int l = (int)__builtin_ctzll(m);
        m &= (m - 1);
        int fs = (l << 3) + wv;  // wave-uniform slot, ascending within wave
        float4 h0 = s_hot4[fs * 4 + 0];
        float4 h1 = s_hot4[fs * 4 + 1];
        float4 h2 = s_hot4[fs * 4 + 2];
        float4 h3 = s_hot4[fs * 4 + 3];
        float w0 = fmaf(h0.x, px, fmaf(h0.y, py, h0.z));
        float w1 = fmaf(h0.w, px, fmaf(h1.x, py, h1.y));
        float w2 = fmaf(h1.z, px, fmaf(h1.w, py, h2.x));
        float minw = fminf(fminf(w0, w1), w2);
        bool inside = minw >= 0.0f;
        float z = fmaf(h2.y, px, fmaf(h2.z, py, h2.w));
        if (inside && z > bestz) { bestz = z; besti = fs; }
        icnt += inside ? 1 : 0;
        // lower bound on dist to boundary: min |w_i| * (area/len_i)
        float db = fminf(fminf(fabsf(w0) * h3.x, fabsf(w1) * h3.y), fabsf(w2) * h3.z);
        bool need = (!inside) & (db < kCut);
        if (__any(need)) {
            float4 v01 = s_vtx4[fs * 2 + 0];
            float4 v2_ = s_vtx4[fs * 2 + 1];
            float e2x = v01.z - v01.x, e2y = v01.w - v01.y;
            float e0x = v2_.x - v01.z, e0y = v2_.y - v01.w;
            float e1x = v01.x - v2_.x, e1y = v01.y - v2_.y;
            float dA = seg_d2(px - v01.x, py - v01.y, e2x, e2y);
            float dB = seg_d2(px - v01.z, py - v01.w, e0x, e0y);
            float dC = seg_d2(px - v2_.x, py - v2_.y, e1x, e1y);
            float d2 = fminf(fminf(dA, dB), dC);
            float p = __expf(-kDelta * d2);
            p = fminf(p, 1.0f - 1e-7f);
            float lp = __logf(1.0f - p);  // == log1p(-p): 1-p exact for p >= 0.5
            lm += need ? lp : 0.0f;
        }
    }
    lm = fmaf((float)icnt, kLogInside, lm);

    s_bz[tid] = bestz;
    s_bi[tid] = besti;
    s_lm[tid] = lm;
    __syncthreads();

    if (tid < 64) {
        float bz = s_bz[tid];
        int bi = s_bi[tid];
        float L = s_lm[tid];
#pragma unroll
        for (int w = 1; w < 8; ++w) {
            float z2 = s_bz[w * 64 + tid];
            int ii = s_bi[w * 64 + tid];
            L += s_lm[w * 64 + tid];
            // first-max semantics: lower compacted slot (== lower orig face) wins ties
            if (z2 > bz || (z2 == bz && ii >= 0 && (unsigned)ii < (unsigned)bi)) {
                bz = z2; bi = ii;
            }
        }
        float improb = 1.0f - expf(L);
        float u = 0.0f, v = 0.0f, mk = 0.0f;
        if (bi >= 0) {
            float4 h0 = s_hot4[bi * 4 + 0];
            float4 h1 = s_hot4[bi * 4 + 1];
            float4 h3 = s_hot4[bi * 4 + 3];
            float c2v = s_hot4[bi * 4 + 2].x;
            float w0 = fmaf(h0.x, px, fmaf(h0.y, py, h0.z));
            float w1 = fmaf(h0.w, px, fmaf(h1.x, py, h1.y));
            float w2 = fmaf(h1.z, px, fmaf(h1.w, py, c2v));
            int of = __float_as_int(h3.w);
            int j0 = faces[of * 3], j1 = faces[of * 3 + 1], j2 = faces[of * 3 + 2];
            const float* ub = uvs + b * kP * 2;
            u = w0 * ub[j0 * 2] + w1 * ub[j1 * 2] + w2 * ub[j2 * 2];
            v = w0 * ub[j0 * 2 + 1] + w1 * ub[j1 * 2 + 1] + w2 * ub[j2 * 2 + 1];
            mk = w0 + w1 + w2;
        }
        float uc = fminf(fmaxf(u, 0.0f), 1.0f);
        float vc = fminf(fmaxf(v, 0.0f), 1.0f);
        float fx = uc * (float)(kTW - 1);
        float fy = (1.0f - vc) * (float)(kTH - 1);
        int xi0 = (int)floorf(fx), yi0 = (int)floorf(fy);
        int xi1 = min(xi0 + 1, kTW - 1), yi1 = min(yi0 + 1, kTH - 1);
        float wx = fx - (float)xi0, wy = fy - (float)yi0;
        float w00 = (1.0f - wx) * (1.0f - wy);
        float w01 = wx * (1.0f - wy);
        float w10 = (1.0f - wx) * wy;
        float w11 = wx * wy;
        int o00 = yi0 * kTW + xi0, o01 = yi0 * kTW + xi1;
        int o10 = yi1 * kTW + xi0, o11 = yi1 * kTW + xi1;
        const float* tb = tex + (size_t)b * 3 * kTH * kTW;
        float cols[3];
#pragma unroll
        for (int c = 0; c < 3; ++c) {
            const float* tc = tb + c * kTH * kTW;
            cols[c] = (tc[o00] * w00 + tc[o01] * w01 + tc[o10] * w10 + tc[o11] * w11) * mk;
        }
        int pix = (b * kH + pyi) * kW + pxi;
        out[pix * 3 + 0] = cols[0];
        out[pix * 3 + 1] = cols[1];
        out[pix * 3 + 2] = cols[2];
        out[kB * kH * kW * 3 + pix] = improb;
    }
}

extern "C" void kernel_launch(void* const* d_in, const int* in_sizes, int n_in,
                              void* d_out, int out_size, void* d_ws, size_t ws_size,
                              hipStream_t stream) {
    const float* pts = (const float*)d_in[0];
    const int* faces = (const int*)d_in[1];
    const float* uvs = (const float*)d_in[2];
    const float* tex = (const float*)d_in[3];
    float* out = (float*)d_out;
    render_all<<<kB * 256, 512, 0, stream>>>(pts, faces, uvs, tex, out);
}